// Round 9
// baseline (99.315 us; speedup 1.0000x reference)
//
#include <hip/hip_runtime.h>

#define BB 32
#define CC 3
#define HH 128
#define WW 128
#define NN 1024
#define KK (CC*HH*WW)        // 49152
#define NROWS (CC*HH)        // 384
#define KSR NROWS            // 384 split-K groups (1 row each)
#define BH 16                // batches per block
#define BSPLIT (BB/BH)       // 2
#define WCH 4                // w-columns per register chunk
#define NCH (WW/WCH)         // 32 chunks per row
#define STEP (1.0f/127.0f)

// ---- per-neuron normalization scale: scale[n] = sqrt(H*W/(Sx*Sy)) ----
__global__ void scale_kernel(const float* __restrict__ mu_x,
                             const float* __restrict__ mu_y,
                             const float* __restrict__ sigma_x,
                             const float* __restrict__ sigma_y,
                             float* __restrict__ scale) {
    int n = blockIdx.x * blockDim.x + threadIdx.x;
    if (n >= NN) return;
    float mux = mu_x[n], muy = mu_y[n];
    float isx = 1.0f / sigma_x[n], isy = 1.0f / sigma_y[n];
    float Sx = 0.f, Sy = 0.f;
    for (int i = 0; i < WW; ++i) {
        float dx = (i * STEP - mux) * isx;
        Sx += __expf(-dx * dx);
        float dy = (i * STEP - muy) * isy;
        Sy += __expf(-dy * dy);
    }
    scale[n] = sqrtf((float)(HH * WW) / (Sx * Sy));
}

// ---- transpose x[B,K] -> xT[K,B] (proven R1 kernel) ----
__global__ void xpose_kernel(const float* __restrict__ x, float* __restrict__ xT) {
    __shared__ float tile[64][BB + 1];
    int k0 = blockIdx.x * 64;
    int lane = threadIdx.x & 63;   // k within tile
    int bgrp = threadIdx.x >> 6;   // 0..3
#pragma unroll
    for (int i = 0; i < 8; ++i) {
        int b = bgrp * 8 + i;
        tile[lane][b] = x[(size_t)b * KK + k0 + lane];
    }
    __syncthreads();
    int b = threadIdx.x & 31;
    int kk0 = threadIdx.x >> 5;    // 0..7
#pragma unroll
    for (int i = 0; i < 8; ++i) {
        int kk = i * 8 + kk0;
        xT[(size_t)(k0 + kk) * BB + b] = tile[kk][b];
    }
}

// ---- main v5: zero-LDS register pipeline + coalesced-atomic epilogue ----
// block = (row g, batch-half b0); wave owns a 256-n slice;
// lane owns n = wv*256 + j*64 + lane (j=0..3) -> atomics are lane-consecutive.
__global__ __launch_bounds__(256) void main_pipe(
    const float* __restrict__ weights,
    const float* __restrict__ xT,
    const float* __restrict__ scale,
    const float* __restrict__ mu_x, const float* __restrict__ mu_y,
    const float* __restrict__ sigma_x, const float* __restrict__ sigma_y,
    float* __restrict__ out)
{
    const int tid  = threadIdx.x;
    const int wv   = tid >> 6;
    const int lane = tid & 63;

    // XCD swizzle: the 2 batch-half siblings of a row -> same XCD, adjacent.
    const int d    = blockIdx.x;             // 0..767
    const int xcd  = d & 7;
    const int slot = d >> 3;                 // 0..95
    const int g    = xcd * (KSR / 8) + (slot >> 1);   // 0..383
    const int b0   = (slot & 1) * BH;
    const int r    = g;
    const int h    = r & (HH - 1);
    const int nbase = wv * 256 + lane;       // j-th n = nbase + j*64

    float mux[4], ax[4], axs[4], Bf[4], gyrow[4];
#pragma unroll
    for (int j = 0; j < 4; ++j) {
        const int n = nbase + j * 64;
        const float mx  = mu_x[n];
        const float sxv = sigma_x[n];
        const float myv = mu_y[n];
        const float syv = sigma_y[n];
        const float scv = scale[n];
        mux[j] = mx;
        ax[j]  = -0.5f / (sxv * sxv);
        axs[j] = ax[j] * STEP;
        Bf[j]  = __expf(2.f * axs[j] * STEP);
        const float ayc = -0.5f / (syv * syv);
        const float dd  = h * STEP - myv;
        gyrow[j] = __expf(ayc * dd * dd) * scv;   // gy[h]*scale folded
    }

    const float* wbase = weights + (size_t)r * WW * NN + nbase;
    const float4* xr4  = (const float4*)xT + (size_t)r * (WW * BB / 4) + (b0 >> 2);
    // per w: xr4[w*8 + q], q = 0..3 (16 batches, wave-uniform -> 1 request)

    float wR[2][4][4];                        // [buf][w-in-chunk][j]
#define WLOAD(BUF, C)                                                   \
    {                                                                   \
        _Pragma("unroll")                                               \
        for (int i = 0; i < 4; ++i) {                                   \
            _Pragma("unroll")                                           \
            for (int j = 0; j < 4; ++j)                                 \
                wR[BUF][i][j] = wbase[(size_t)((C)*WCH + i) * NN + j * 64]; \
        }                                                               \
    }

    float acc[BH][4];
#pragma unroll
    for (int b = 0; b < BH; ++b)
#pragma unroll
        for (int j = 0; j < 4; ++j) acc[b][j] = 0.f;

    float g4[4], r4[4];
    auto resync = [&](int w0) {              // fresh exps, span <= 16 w
        const float w0s = (float)w0 * STEP;
#pragma unroll
        for (int j = 0; j < 4; ++j) {
            const float dd = w0s - mux[j];
            g4[j] = __expf(ax[j] * dd * dd) * gyrow[j];
            r4[j] = __expf(axs[j] * (2.f * dd + STEP));
        }
    };

#define FMAQ(XC, B)                                                     \
    {                                                                   \
        acc[B][0] = fmaf(XC, t0, acc[B][0]);                            \
        acc[B][1] = fmaf(XC, t1, acc[B][1]);                            \
        acc[B][2] = fmaf(XC, t2, acc[B][2]);                            \
        acc[B][3] = fmaf(XC, t3, acc[B][3]);                            \
    }

#define CHUNK(BUF, C)                                                   \
    {                                                                   \
        if (((C) & 3) == 0) resync((C) * WCH);                          \
        _Pragma("unroll")                                               \
        for (int i = 0; i < 4; ++i) {                                   \
            const int w = (C) * WCH + i;                                \
            const float4 xq0 = xr4[w*8 + 0];                            \
            const float4 xq1 = xr4[w*8 + 1];                            \
            const float4 xq2 = xr4[w*8 + 2];                            \
            const float4 xq3 = xr4[w*8 + 3];                            \
            const float t0 = g4[0] * wR[BUF][i][0];                     \
            const float t1 = g4[1] * wR[BUF][i][1];                     \
            const float t2 = g4[2] * wR[BUF][i][2];                     \
            const float t3 = g4[3] * wR[BUF][i][3];                     \
            FMAQ(xq0.x,  0) FMAQ(xq0.y,  1) FMAQ(xq0.z,  2) FMAQ(xq0.w,  3) \
            FMAQ(xq1.x,  4) FMAQ(xq1.y,  5) FMAQ(xq1.z,  6) FMAQ(xq1.w,  7) \
            FMAQ(xq2.x,  8) FMAQ(xq2.y,  9) FMAQ(xq2.z, 10) FMAQ(xq2.w, 11) \
            FMAQ(xq3.x, 12) FMAQ(xq3.y, 13) FMAQ(xq3.z, 14) FMAQ(xq3.w, 15) \
            g4[0] *= r4[0]; g4[1] *= r4[1]; g4[2] *= r4[2]; g4[3] *= r4[3]; \
            r4[0] *= Bf[0]; r4[1] *= Bf[1]; r4[2] *= Bf[2]; r4[3] *= Bf[3]; \
        }                                                               \
    }

    WLOAD(0, 0);
    for (int c = 0; c < NCH; c += 2) {
        WLOAD(1, c + 1);                     // prefetch next chunk (regs)
        CHUNK(0, c);                         // compute current
        if (c + 2 < NCH) WLOAD(0, c + 2);
        CHUNK(1, c + 1);
    }
#undef CHUNK
#undef FMAQ
#undef WLOAD

    // coalesced atomics: per (b,j) one wave-instruction covering 256 B
    // contiguous; rotate b-start by g to spread L2 line contention.
    const int rot = g & (BH - 1);
#pragma unroll
    for (int bb = 0; bb < BH; ++bb) {
        const int b = (bb + rot) & (BH - 1);
        float* op = out + (size_t)(b0 + b) * NN + nbase;
#pragma unroll
        for (int j = 0; j < 4; ++j)
            atomicAdd(op + j * 64, acc[b][j]);
    }
}

// ---- fallback (atomic, self-contained) — proven R3 structure ----
__global__ __launch_bounds__(256) void main_fallback(
    const float* __restrict__ weights,
    const float* __restrict__ x,
    const float* __restrict__ mu_x, const float* __restrict__ mu_y,
    const float* __restrict__ sigma_x, const float* __restrict__ sigma_y,
    float* __restrict__ dst)
{
    __shared__ float tile[2][WW][8];
    const int tid = threadIdx.x;
    const int g   = blockIdx.x;
    const int b0  = blockIdx.y * 8;
    const int r0  = g * 2;

    {
        const int b = tid & 7;
        const int c = tid >> 3;
        const float* xp = x + (size_t)(b0 + b) * KK + (size_t)r0 * WW + c * 8;
        const float4 v0 = ((const float4*)xp)[0];
        const float4 v1 = ((const float4*)xp)[1];
        const int row = (c * 8) >> 7;
        const int w   = (c * 8) & (WW - 1);
        tile[row][w+0][b] = v0.x; tile[row][w+1][b] = v0.y;
        tile[row][w+2][b] = v0.z; tile[row][w+3][b] = v0.w;
        tile[row][w+4][b] = v1.x; tile[row][w+5][b] = v1.y;
        tile[row][w+6][b] = v1.z; tile[row][w+7][b] = v1.w;
    }

    float4 mux4 = ((const float4*)mu_x)[tid];
    float4 muy4 = ((const float4*)mu_y)[tid];
    float4 sx4  = ((const float4*)sigma_x)[tid];
    float4 sy4  = ((const float4*)sigma_y)[tid];
    float4 ax4, ay4, sc4;
    ax4.x=-0.5f/(sx4.x*sx4.x); ax4.y=-0.5f/(sx4.y*sx4.y);
    ax4.z=-0.5f/(sx4.z*sx4.z); ax4.w=-0.5f/(sx4.w*sx4.w);
    ay4.x=-0.5f/(sy4.x*sy4.x); ay4.y=-0.5f/(sy4.y*sy4.y);
    ay4.z=-0.5f/(sy4.z*sy4.z); ay4.w=-0.5f/(sy4.w*sy4.w);
    {
        float Sx[4]={0,0,0,0}, Sy[4]={0,0,0,0};
        for (int i = 0; i < WW; ++i) {
            float pp = i * STEP, dd;
            dd=pp-mux4.x; Sx[0]+=__expf(2.f*ax4.x*dd*dd);
            dd=pp-mux4.y; Sx[1]+=__expf(2.f*ax4.y*dd*dd);
            dd=pp-mux4.z; Sx[2]+=__expf(2.f*ax4.z*dd*dd);
            dd=pp-mux4.w; Sx[3]+=__expf(2.f*ax4.w*dd*dd);
            dd=pp-muy4.x; Sy[0]+=__expf(2.f*ay4.x*dd*dd);
            dd=pp-muy4.y; Sy[1]+=__expf(2.f*ay4.y*dd*dd);
            dd=pp-muy4.z; Sy[2]+=__expf(2.f*ay4.z*dd*dd);
            dd=pp-muy4.w; Sy[3]+=__expf(2.f*ay4.w*dd*dd);
        }
        sc4.x = sqrtf((float)(HH*WW)/(Sx[0]*Sy[0]));
        sc4.y = sqrtf((float)(HH*WW)/(Sx[1]*Sy[1]));
        sc4.z = sqrtf((float)(HH*WW)/(Sx[2]*Sy[2]));
        sc4.w = sqrtf((float)(HH*WW)/(Sx[3]*Sy[3]));
    }
    __syncthreads();

    float acc[8][4];
#pragma unroll
    for (int b = 0; b < 8; ++b)
        acc[b][0] = acc[b][1] = acc[b][2] = acc[b][3] = 0.f;

#pragma unroll
    for (int rr = 0; rr < 2; ++rr) {
        const int rrow = r0 + rr;
        const int hh = rrow & (HH - 1);
        float4 gys;
        {
            float hp = hh * STEP, dd;
            dd=hp-muy4.x; gys.x = __expf(ay4.x*dd*dd) * sc4.x;
            dd=hp-muy4.y; gys.y = __expf(ay4.y*dd*dd) * sc4.y;
            dd=hp-muy4.z; gys.z = __expf(ay4.z*dd*dd) * sc4.z;
            dd=hp-muy4.w; gys.w = __expf(ay4.w*dd*dd) * sc4.w;
        }
        const float4* wp = (const float4*)(weights + (size_t)rrow * WW * NN) + tid;
        float racc[8][4];
#pragma unroll
        for (int b = 0; b < 8; ++b)
            racc[b][0] = racc[b][1] = racc[b][2] = racc[b][3] = 0.f;
        for (int w = 0; w < WW; ++w) {
            const float4 wt = wp[(size_t)w * (NN/4)];
            float pp = w * STEP, dd;
            float4 t;
            dd=pp-mux4.x; t.x = __expf(ax4.x*dd*dd) * wt.x;
            dd=pp-mux4.y; t.y = __expf(ax4.y*dd*dd) * wt.y;
            dd=pp-mux4.z; t.z = __expf(ax4.z*dd*dd) * wt.z;
            dd=pp-mux4.w; t.w = __expf(ax4.w*dd*dd) * wt.w;
            const float4* trp = (const float4*)&tile[rr][w][0];
            float xs[8];
            ((float4*)xs)[0] = trp[0]; ((float4*)xs)[1] = trp[1];
#pragma unroll
            for (int b = 0; b < 8; ++b) {
                racc[b][0] = fmaf(xs[b], t.x, racc[b][0]);
                racc[b][1] = fmaf(xs[b], t.y, racc[b][1]);
                racc[b][2] = fmaf(xs[b], t.z, racc[b][2]);
                racc[b][3] = fmaf(xs[b], t.w, racc[b][3]);
            }
        }
#pragma unroll
        for (int b = 0; b < 8; ++b) {
            acc[b][0] = fmaf(gys.x, racc[b][0], acc[b][0]);
            acc[b][1] = fmaf(gys.y, racc[b][1], acc[b][1]);
            acc[b][2] = fmaf(gys.z, racc[b][2], acc[b][2]);
            acc[b][3] = fmaf(gys.w, racc[b][3], acc[b][3]);
        }
    }

    float* op = dst + (size_t)b0 * NN + tid * 4;
#pragma unroll
    for (int b = 0; b < 8; ++b) {
        atomicAdd(op + (size_t)b * NN + 0, acc[b][0]);
        atomicAdd(op + (size_t)b * NN + 1, acc[b][1]);
        atomicAdd(op + (size_t)b * NN + 2, acc[b][2]);
        atomicAdd(op + (size_t)b * NN + 3, acc[b][3]);
    }
}

extern "C" void kernel_launch(void* const* d_in, const int* in_sizes, int n_in,
                              void* d_out, int out_size, void* d_ws, size_t ws_size,
                              hipStream_t stream) {
    const float* x       = (const float*)d_in[0];
    const float* mu_x    = (const float*)d_in[1];
    const float* mu_y    = (const float*)d_in[2];
    const float* sigma_x = (const float*)d_in[3];
    const float* sigma_y = (const float*)d_in[4];
    const float* weights = (const float*)d_in[5];
    float* out = (float*)d_out;

    float* scale = (float*)d_ws;                          // 4 KB
    float* xT    = (float*)((char*)d_ws + 4096);          // 6.3 MB
    const size_t need = 4096 + sizeof(float) * (size_t)KK * BB;

    // out is accumulated atomically -> zero it every call (graph-safe)
    hipMemsetAsync(d_out, 0, (size_t)out_size * sizeof(float), stream);

    if (ws_size >= need) {
        scale_kernel<<<(NN + 255) / 256, 256, 0, stream>>>(mu_x, mu_y, sigma_x, sigma_y, scale);
        xpose_kernel<<<KK / 64, 256, 0, stream>>>(x, xT);
        main_pipe<<<KSR * BSPLIT, 256, 0, stream>>>(weights, xT, scale,
                                                    mu_x, mu_y, sigma_x, sigma_y, out);
    } else {
        dim3 grid(NROWS / 2, 4);
        main_fallback<<<grid, 256, 0, stream>>>(weights, x,
                                                mu_x, mu_y, sigma_x, sigma_y, out);
    }
}

// Round 10
// 76.652 us; speedup vs baseline: 1.2957x; 1.2957x over previous
//
#include <hip/hip_runtime.h>

#define BB 32
#define CC 3
#define HH 128
#define WW 128
#define NN 1024
#define KK (CC*HH*WW)        // 49152
#define NROWS (CC*HH)        // 384
#define KSR NROWS            // 384 split-K groups (1 row each)
#define BH 16                // batches per block
#define BSPLIT (BB/BH)       // 2
#define WCH 4                // w-columns per register chunk
#define NCH (WW/WCH)         // 32 chunks per row
#define SG 8                 // s-groups in reduce stage 1
#define STEP (1.0f/127.0f)

// ---- per-neuron normalization scale: scale[n] = sqrt(H*W/(Sx*Sy)) ----
__global__ void scale_kernel(const float* __restrict__ mu_x,
                             const float* __restrict__ mu_y,
                             const float* __restrict__ sigma_x,
                             const float* __restrict__ sigma_y,
                             float* __restrict__ scale) {
    int n = blockIdx.x * blockDim.x + threadIdx.x;
    if (n >= NN) return;
    float mux = mu_x[n], muy = mu_y[n];
    float isx = 1.0f / sigma_x[n], isy = 1.0f / sigma_y[n];
    float Sx = 0.f, Sy = 0.f;
    for (int i = 0; i < WW; ++i) {
        float dx = (i * STEP - mux) * isx;
        Sx += __expf(-dx * dx);
        float dy = (i * STEP - muy) * isy;
        Sy += __expf(-dy * dy);
    }
    scale[n] = sqrtf((float)(HH * WW) / (Sx * Sy));
}

// ---- transpose x[B,K] -> xT[K,B] (proven R1 kernel) ----
__global__ void xpose_kernel(const float* __restrict__ x, float* __restrict__ xT) {
    __shared__ float tile[64][BB + 1];
    int k0 = blockIdx.x * 64;
    int lane = threadIdx.x & 63;   // k within tile
    int bgrp = threadIdx.x >> 6;   // 0..3
#pragma unroll
    for (int i = 0; i < 8; ++i) {
        int b = bgrp * 8 + i;
        tile[lane][b] = x[(size_t)b * KK + k0 + lane];
    }
    __syncthreads();
    int b = threadIdx.x & 31;
    int kk0 = threadIdx.x >> 5;    // 0..7
#pragma unroll
    for (int i = 0; i < 8; ++i) {
        int kk = i * 8 + kk0;
        xT[(size_t)(k0 + kk) * BB + b] = tile[kk][b];
    }
}

// ---- main v6: zero-LDS register pipeline, weights AND x both prefetched ----
// block = (row g, batch-half b0); wave owns a 256-n slice; lane owns 4 n.
// Weights double-buffered per 4-w chunk; x ping-pong buffered per w (xqA/xqB,
// no copy chains, all compile-time indices).
__global__ __launch_bounds__(256) void main_pipe(
    const float* __restrict__ weights,
    const float* __restrict__ xT,
    const float* __restrict__ scale,
    const float* __restrict__ mu_x, const float* __restrict__ mu_y,
    const float* __restrict__ sigma_x, const float* __restrict__ sigma_y,
    float* __restrict__ part)
{
    const int tid  = threadIdx.x;
    const int wv   = tid >> 6;
    const int lane = tid & 63;

    // XCD swizzle: the 2 batch-half siblings of a row -> same XCD, adjacent.
    const int d    = blockIdx.x;             // 0..767
    const int xcd  = d & 7;
    const int slot = d >> 3;                 // 0..95
    const int g    = xcd * (KSR / 8) + (slot >> 1);   // 0..383
    const int b0   = (slot & 1) * BH;
    const int r    = g;
    const int h    = r & (HH - 1);
    const int nq   = wv * 64 + lane;         // float4 index into n-arrays

    const float4 mux = ((const float4*)mu_x)[nq];
    const float4 sx4 = ((const float4*)sigma_x)[nq];
    const float4 muy = ((const float4*)mu_y)[nq];
    const float4 sy4 = ((const float4*)sigma_y)[nq];
    const float4 sc4 = ((const float4*)scale)[nq];

    float4 ax, axs, Bf, gyrow;
    ax.x = -0.5f/(sx4.x*sx4.x); ax.y = -0.5f/(sx4.y*sx4.y);
    ax.z = -0.5f/(sx4.z*sx4.z); ax.w = -0.5f/(sx4.w*sx4.w);
    axs.x = ax.x*STEP; axs.y = ax.y*STEP; axs.z = ax.z*STEP; axs.w = ax.w*STEP;
    Bf.x = __expf(2.f*axs.x*STEP); Bf.y = __expf(2.f*axs.y*STEP);
    Bf.z = __expf(2.f*axs.z*STEP); Bf.w = __expf(2.f*axs.w*STEP);
    {   // gy[h]*scale inline
        const float hp = h * STEP;
        float ayc, dd;
        ayc = -0.5f/(sy4.x*sy4.x); dd = hp-muy.x; gyrow.x = __expf(ayc*dd*dd)*sc4.x;
        ayc = -0.5f/(sy4.y*sy4.y); dd = hp-muy.y; gyrow.y = __expf(ayc*dd*dd)*sc4.y;
        ayc = -0.5f/(sy4.z*sy4.z); dd = hp-muy.z; gyrow.z = __expf(ayc*dd*dd)*sc4.z;
        ayc = -0.5f/(sy4.w*sy4.w); dd = hp-muy.w; gyrow.w = __expf(ayc*dd*dd)*sc4.w;
    }

    const float* wbase = weights + (size_t)r * WW * NN + nq * 4;
    const float4* xr4  = (const float4*)xT + (size_t)r * (WW * BB / 4) + (b0 >> 2);
    // per w: xr4[w*8 + q], q = 0..3 (16 batches, wave-uniform address)

    float4 wR[2][4];                          // double-buffered weight quads
#define WLOAD(BUF, C)                                                   \
    {                                                                   \
        _Pragma("unroll")                                               \
        for (int i = 0; i < 4; ++i)                                     \
            wR[BUF][i] = *(const float4*)(wbase + (size_t)((C)*WCH + i) * NN); \
    }

    float4 xqA[4], xqB[4];                    // ping-pong x buffers
#define XLD(ARR, W)                                                     \
    {                                                                   \
        const int wn_ = ((W) < WW) ? (W) : 0;  /* clamp: no OOB */      \
        ARR[0] = xr4[wn_*8 + 0];                                        \
        ARR[1] = xr4[wn_*8 + 1];                                        \
        ARR[2] = xr4[wn_*8 + 2];                                        \
        ARR[3] = xr4[wn_*8 + 3];                                        \
    }

    float4 acc[BH];
#pragma unroll
    for (int b = 0; b < BH; ++b) acc[b] = make_float4(0.f, 0.f, 0.f, 0.f);

    float4 g4, r4;
    auto resync = [&](int w0) {              // fresh exps, span <= 16 w
        const float w0s = (float)w0 * STEP;
        float dd;
        dd = w0s - mux.x; g4.x = __expf(ax.x*dd*dd)*gyrow.x; r4.x = __expf(axs.x*(2.f*dd+STEP));
        dd = w0s - mux.y; g4.y = __expf(ax.y*dd*dd)*gyrow.y; r4.y = __expf(axs.y*(2.f*dd+STEP));
        dd = w0s - mux.z; g4.z = __expf(ax.z*dd*dd)*gyrow.z; r4.z = __expf(axs.z*(2.f*dd+STEP));
        dd = w0s - mux.w; g4.w = __expf(ax.w*dd*dd)*gyrow.w; r4.w = __expf(axs.w*(2.f*dd+STEP));
    };

#define FMAQ(XQ, A0)                                                    \
    {                                                                   \
        acc[A0+0].x = fmaf(XQ.x, t.x, acc[A0+0].x);                     \
        acc[A0+0].y = fmaf(XQ.x, t.y, acc[A0+0].y);                     \
        acc[A0+0].z = fmaf(XQ.x, t.z, acc[A0+0].z);                     \
        acc[A0+0].w = fmaf(XQ.x, t.w, acc[A0+0].w);                     \
        acc[A0+1].x = fmaf(XQ.y, t.x, acc[A0+1].x);                     \
        acc[A0+1].y = fmaf(XQ.y, t.y, acc[A0+1].y);                     \
        acc[A0+1].z = fmaf(XQ.y, t.z, acc[A0+1].z);                     \
        acc[A0+1].w = fmaf(XQ.y, t.w, acc[A0+1].w);                     \
        acc[A0+2].x = fmaf(XQ.z, t.x, acc[A0+2].x);                     \
        acc[A0+2].y = fmaf(XQ.z, t.y, acc[A0+2].y);                     \
        acc[A0+2].z = fmaf(XQ.z, t.z, acc[A0+2].z);                     \
        acc[A0+2].w = fmaf(XQ.z, t.w, acc[A0+2].w);                     \
        acc[A0+3].x = fmaf(XQ.w, t.x, acc[A0+3].x);                     \
        acc[A0+3].y = fmaf(XQ.w, t.y, acc[A0+3].y);                     \
        acc[A0+3].z = fmaf(XQ.w, t.z, acc[A0+3].z);                     \
        acc[A0+3].w = fmaf(XQ.w, t.w, acc[A0+3].w);                     \
    }

#define WSTEP(ARR, WBUF, I)                                             \
    {                                                                   \
        const float4 wt = wR[WBUF][I];                                  \
        float4 t;                                                       \
        t.x = g4.x * wt.x; t.y = g4.y * wt.y;                           \
        t.z = g4.z * wt.z; t.w = g4.w * wt.w;                           \
        FMAQ(ARR[0], 0)                                                 \
        FMAQ(ARR[1], 4)                                                 \
        FMAQ(ARR[2], 8)                                                 \
        FMAQ(ARR[3], 12)                                                \
        g4.x *= r4.x; g4.y *= r4.y; g4.z *= r4.z; g4.w *= r4.w;         \
        r4.x *= Bf.x; r4.y *= Bf.y; r4.z *= Bf.z; r4.w *= Bf.w;         \
    }

// Each XLD issues one w ahead of the WSTEP that consumes the OTHER buffer.
#define CHUNK(WBUF, C)                                                  \
    {                                                                   \
        if (((C) & 3) == 0) resync((C) * WCH);                          \
        XLD(xqB, (C)*4 + 1)                                             \
        WSTEP(xqA, WBUF, 0)                                             \
        XLD(xqA, (C)*4 + 2)                                             \
        WSTEP(xqB, WBUF, 1)                                             \
        XLD(xqB, (C)*4 + 3)                                             \
        WSTEP(xqA, WBUF, 2)                                             \
        XLD(xqA, (C)*4 + 4)  /* first w of next chunk */                \
        WSTEP(xqB, WBUF, 3)                                             \
    }

    WLOAD(0, 0);
    XLD(xqA, 0)
    for (int c = 0; c < NCH; c += 2) {
        WLOAD(1, c + 1);                     // prefetch next weight chunk
        CHUNK(0, c);                         // compute current
        if (c + 2 < NCH) WLOAD(0, c + 2);
        CHUNK(1, c + 1);
    }
#undef CHUNK
#undef WSTEP
#undef FMAQ
#undef XLD
#undef WLOAD

    // coalesced float4 stores into this block's private partial slice
    float* pp = part + ((size_t)g * BB + b0) * NN + (tid << 2);
#pragma unroll
    for (int b = 0; b < BH; ++b)
        *(float4*)(pp + (size_t)b * NN) = acc[b];
}

// ---- reduce stage 1: part2[sg][cq] = sum over 48 s of part[s][cq] ----
__global__ __launch_bounds__(256) void reduce1_kernel(const float* __restrict__ part,
                                                      float* __restrict__ part2) {
    const int sg = blockIdx.x >> 5;                       // 0..7
    const int cq = (blockIdx.x & 31) * 256 + threadIdx.x; // cell-quads
    const int s0 = sg * (KSR / SG);
    float4 a = make_float4(0.f, 0.f, 0.f, 0.f);
#pragma unroll 4
    for (int s = 0; s < KSR / SG; ++s) {
        const float4 v = *(const float4*)(part + (size_t)(s0 + s) * (BB * NN) + cq * 4);
        a.x += v.x; a.y += v.y; a.z += v.z; a.w += v.w;
    }
    *(float4*)(part2 + ((size_t)sg * (BB * NN) + cq * 4)) = a;
}

// ---- reduce stage 2: out[cq] = sum over 8 s-groups ----
__global__ __launch_bounds__(256) void reduce2_kernel(const float* __restrict__ part2,
                                                      float* __restrict__ out) {
    const int cq = blockIdx.x * 256 + threadIdx.x;
    float4 a = make_float4(0.f, 0.f, 0.f, 0.f);
#pragma unroll
    for (int sgi = 0; sgi < SG; ++sgi) {
        const float4 v = *(const float4*)(part2 + (size_t)sgi * (BB * NN) + cq * 4);
        a.x += v.x; a.y += v.y; a.z += v.z; a.w += v.w;
    }
    *(float4*)(out + cq * 4) = a;
}

// ---- fallback (atomic, self-contained) — proven R3 structure ----
__global__ __launch_bounds__(256) void main_fallback(
    const float* __restrict__ weights,
    const float* __restrict__ x,
    const float* __restrict__ mu_x, const float* __restrict__ mu_y,
    const float* __restrict__ sigma_x, const float* __restrict__ sigma_y,
    float* __restrict__ dst)
{
    __shared__ float tile[2][WW][8];
    const int tid = threadIdx.x;
    const int g   = blockIdx.x;
    const int b0  = blockIdx.y * 8;
    const int r0  = g * 2;

    {
        const int b = tid & 7;
        const int c = tid >> 3;
        const float* xp = x + (size_t)(b0 + b) * KK + (size_t)r0 * WW + c * 8;
        const float4 v0 = ((const float4*)xp)[0];
        const float4 v1 = ((const float4*)xp)[1];
        const int row = (c * 8) >> 7;
        const int w   = (c * 8) & (WW - 1);
        tile[row][w+0][b] = v0.x; tile[row][w+1][b] = v0.y;
        tile[row][w+2][b] = v0.z; tile[row][w+3][b] = v0.w;
        tile[row][w+4][b] = v1.x; tile[row][w+5][b] = v1.y;
        tile[row][w+6][b] = v1.z; tile[row][w+7][b] = v1.w;
    }

    float4 mux4 = ((const float4*)mu_x)[tid];
    float4 muy4 = ((const float4*)mu_y)[tid];
    float4 sx4  = ((const float4*)sigma_x)[tid];
    float4 sy4  = ((const float4*)sigma_y)[tid];
    float4 ax4, ay4, sc4;
    ax4.x=-0.5f/(sx4.x*sx4.x); ax4.y=-0.5f/(sx4.y*sx4.y);
    ax4.z=-0.5f/(sx4.z*sx4.z); ax4.w=-0.5f/(sx4.w*sx4.w);
    ay4.x=-0.5f/(sy4.x*sy4.x); ay4.y=-0.5f/(sy4.y*sy4.y);
    ay4.z=-0.5f/(sy4.z*sy4.z); ay4.w=-0.5f/(sy4.w*sy4.w);
    {
        float Sx[4]={0,0,0,0}, Sy[4]={0,0,0,0};
        for (int i = 0; i < WW; ++i) {
            float pp = i * STEP, dd;
            dd=pp-mux4.x; Sx[0]+=__expf(2.f*ax4.x*dd*dd);
            dd=pp-mux4.y; Sx[1]+=__expf(2.f*ax4.y*dd*dd);
            dd=pp-mux4.z; Sx[2]+=__expf(2.f*ax4.z*dd*dd);
            dd=pp-mux4.w; Sx[3]+=__expf(2.f*ax4.w*dd*dd);
            dd=pp-muy4.x; Sy[0]+=__expf(2.f*ay4.x*dd*dd);
            dd=pp-muy4.y; Sy[1]+=__expf(2.f*ay4.y*dd*dd);
            dd=pp-muy4.z; Sy[2]+=__expf(2.f*ay4.z*dd*dd);
            dd=pp-muy4.w; Sy[3]+=__expf(2.f*ay4.w*dd*dd);
        }
        sc4.x = sqrtf((float)(HH*WW)/(Sx[0]*Sy[0]));
        sc4.y = sqrtf((float)(HH*WW)/(Sx[1]*Sy[1]));
        sc4.z = sqrtf((float)(HH*WW)/(Sx[2]*Sy[2]));
        sc4.w = sqrtf((float)(HH*WW)/(Sx[3]*Sy[3]));
    }
    __syncthreads();

    float acc[8][4];
#pragma unroll
    for (int b = 0; b < 8; ++b)
        acc[b][0] = acc[b][1] = acc[b][2] = acc[b][3] = 0.f;

#pragma unroll
    for (int rr = 0; rr < 2; ++rr) {
        const int rrow = r0 + rr;
        const int hh = rrow & (HH - 1);
        float4 gys;
        {
            float hp = hh * STEP, dd;
            dd=hp-muy4.x; gys.x = __expf(ay4.x*dd*dd) * sc4.x;
            dd=hp-muy4.y; gys.y = __expf(ay4.y*dd*dd) * sc4.y;
            dd=hp-muy4.z; gys.z = __expf(ay4.z*dd*dd) * sc4.z;
            dd=hp-muy4.w; gys.w = __expf(ay4.w*dd*dd) * sc4.w;
        }
        const float4* wp = (const float4*)(weights + (size_t)rrow * WW * NN) + tid;
        float racc[8][4];
#pragma unroll
        for (int b = 0; b < 8; ++b)
            racc[b][0] = racc[b][1] = racc[b][2] = racc[b][3] = 0.f;
        for (int w = 0; w < WW; ++w) {
            const float4 wt = wp[(size_t)w * (NN/4)];
            float pp = w * STEP, dd;
            float4 t;
            dd=pp-mux4.x; t.x = __expf(ax4.x*dd*dd) * wt.x;
            dd=pp-mux4.y; t.y = __expf(ax4.y*dd*dd) * wt.y;
            dd=pp-mux4.z; t.z = __expf(ax4.z*dd*dd) * wt.z;
            dd=pp-mux4.w; t.w = __expf(ax4.w*dd*dd) * wt.w;
            const float4* trp = (const float4*)&tile[rr][w][0];
            float xs[8];
            ((float4*)xs)[0] = trp[0]; ((float4*)xs)[1] = trp[1];
#pragma unroll
            for (int b = 0; b < 8; ++b) {
                racc[b][0] = fmaf(xs[b], t.x, racc[b][0]);
                racc[b][1] = fmaf(xs[b], t.y, racc[b][1]);
                racc[b][2] = fmaf(xs[b], t.z, racc[b][2]);
                racc[b][3] = fmaf(xs[b], t.w, racc[b][3]);
            }
        }
#pragma unroll
        for (int b = 0; b < 8; ++b) {
            acc[b][0] = fmaf(gys.x, racc[b][0], acc[b][0]);
            acc[b][1] = fmaf(gys.y, racc[b][1], acc[b][1]);
            acc[b][2] = fmaf(gys.z, racc[b][2], acc[b][2]);
            acc[b][3] = fmaf(gys.w, racc[b][3], acc[b][3]);
        }
    }

    float* op = dst + (size_t)b0 * NN + tid * 4;
#pragma unroll
    for (int b = 0; b < 8; ++b) {
        atomicAdd(op + (size_t)b * NN + 0, acc[b][0]);
        atomicAdd(op + (size_t)b * NN + 1, acc[b][1]);
        atomicAdd(op + (size_t)b * NN + 2, acc[b][2]);
        atomicAdd(op + (size_t)b * NN + 3, acc[b][3]);
    }
}

extern "C" void kernel_launch(void* const* d_in, const int* in_sizes, int n_in,
                              void* d_out, int out_size, void* d_ws, size_t ws_size,
                              hipStream_t stream) {
    const float* x       = (const float*)d_in[0];
    const float* mu_x    = (const float*)d_in[1];
    const float* mu_y    = (const float*)d_in[2];
    const float* sigma_x = (const float*)d_in[3];
    const float* sigma_y = (const float*)d_in[4];
    const float* weights = (const float*)d_in[5];
    float* out = (float*)d_out;

    float* scale = (float*)d_ws;                          // 4 KB
    float* xT    = (float*)((char*)d_ws + 4096);          // 6.3 MB
    float* part  = xT + (size_t)KK * BB;                  // 50.3 MB
    float* part2 = part + (size_t)KSR * BB * NN;          // 1 MB
    const size_t need = 4096 +
        sizeof(float) * ((size_t)KK * BB + (size_t)KSR * BB * NN + (size_t)SG * BB * NN);

    if (ws_size >= need) {
        scale_kernel<<<(NN + 255) / 256, 256, 0, stream>>>(mu_x, mu_y, sigma_x, sigma_y, scale);
        xpose_kernel<<<KK / 64, 256, 0, stream>>>(x, xT);
        main_pipe<<<KSR * BSPLIT, 256, 0, stream>>>(weights, xT, scale,
                                                    mu_x, mu_y, sigma_x, sigma_y, part);
        reduce1_kernel<<<32 * SG, 256, 0, stream>>>(part, part2);
        reduce2_kernel<<<BB * NN / 4 / 256, 256, 0, stream>>>(part2, out);
    } else {
        hipMemsetAsync(d_out, 0, (size_t)out_size * sizeof(float), stream);
        dim3 grid(NROWS / 2, 4);
        main_fallback<<<grid, 256, 0, stream>>>(weights, x,
                                                mu_x, mu_y, sigma_x, sigma_y, out);
    }
}